// Round 10
// baseline (215.598 us; speedup 1.0000x reference)
//
#include <hip/hip_runtime.h>
#include <math.h>

#define SEQ   2048
#define BATCH 64
#define HDIM  512
#define EDIM  256
#define VOCAB 50257
#define BH    (BATCH * HDIM)   // 32768
#define G3    (3 * HDIM)       // 1536
#define NCOL  (2 * G3)         // 3072 combined gate columns (ih | hh)
#define P32   32               // block-level partials per batch
#define KS    4                // gru K-chunks

typedef __attribute__((ext_vector_type(4))) float f32x4;
typedef __attribute__((ext_vector_type(8))) short bf16x8;

__device__ __forceinline__ unsigned short f2bf(float x) {
    unsigned int u = __float_as_uint(x);
    u += 0x7fffu + ((u >> 16) & 1u);   // round-to-nearest-even
    return (unsigned short)(u >> 16);
}

__device__ __forceinline__ bf16x8 pack8(float4 a, float4 b) {
    bf16x8 r;
    r[0] = (short)f2bf(a.x); r[1] = (short)f2bf(a.y);
    r[2] = (short)f2bf(a.z); r[3] = (short)f2bf(a.w);
    r[4] = (short)f2bf(b.x); r[5] = (short)f2bf(b.y);
    r[6] = (short)f2bf(b.z); r[7] = (short)f2bf(b.w);
    return r;
}

__device__ __forceinline__ bf16x8 cvt8(const float* p) {
    return pack8(*(const float4*)p, *(const float4*)(p + 4));
}

// ---------------------------------------------------------------------------
// Kernel 1: flash attention partials + block (4-wave) combine + LAST-BLOCK
// batch combine (split-K fixup). Plain cached float4 loads (NT loads were a
// 3x regression -- R9 post-mortem: nt bypasses L2 sector combining).
// ---------------------------------------------------------------------------
__global__ __launch_bounds__(256)
void attn_partial(const float* __restrict__ enc, const float* __restrict__ dec,
                  const float* __restrict__ emb, const int* __restrict__ inputs,
                  unsigned* __restrict__ ticket,
                  float* __restrict__ pm, float* __restrict__ pl,
                  float* __restrict__ pacc,
                  unsigned short* __restrict__ xbf,
                  unsigned short* __restrict__ d0bf,
                  unsigned short* __restrict__ d1bf) {
    __shared__ float sacc[4][HDIM];
    __shared__ float sml[8];
    __shared__ unsigned s_old;
    __shared__ float cs[P32];
    __shared__ float s_inv;

    const int lane = threadIdx.x & 63;
    const int w = threadIdx.x >> 6;
    const int p = blockIdx.x;            // 0..31
    const int b = blockIdx.y;
    const int s0 = (p * 4 + w) * 16;
    const float scale = 0.044194173824159216f; // 1/sqrt(512)

    const float4* qp = (const float4*)(dec + BH + (size_t)b * HDIM + 8 * lane);
    float4 q0 = qp[0], q1 = qp[1];
    float qa[8] = {q0.x, q0.y, q0.z, q0.w, q1.x, q1.y, q1.z, q1.w};

    float m = -INFINITY, l = 0.f;
    float acc[8] = {0.f, 0.f, 0.f, 0.f, 0.f, 0.f, 0.f, 0.f};

    #pragma unroll 2
    for (int r = 0; r < 16; r += 4) {
        float va[4][8];
        #pragma unroll
        for (int j = 0; j < 4; ++j) {
            const float4* vp = (const float4*)(enc +
                ((size_t)(s0 + r + j) * BATCH + b) * HDIM + 8 * lane);
            float4 t0 = vp[0], t1 = vp[1];
            va[j][0] = t0.x; va[j][1] = t0.y; va[j][2] = t0.z; va[j][3] = t0.w;
            va[j][4] = t1.x; va[j][5] = t1.y; va[j][6] = t1.z; va[j][7] = t1.w;
        }
        float e[4];
        #pragma unroll
        for (int j = 0; j < 4; ++j) {
            float d = 0.f;
            #pragma unroll
            for (int i = 0; i < 8; ++i) d = fmaf(va[j][i], qa[i], d);
            e[j] = d;
        }
        #pragma unroll
        for (int off = 32; off > 0; off >>= 1) {
            #pragma unroll
            for (int j = 0; j < 4; ++j) e[j] += __shfl_xor(e[j], off, 64);
        }
        #pragma unroll
        for (int j = 0; j < 4; ++j) e[j] *= scale;
        float m4 = fmaxf(fmaxf(e[0], e[1]), fmaxf(e[2], e[3]));
        float em = fmaxf(m, m4);
        float f  = __expf(m - em);
        float w0 = __expf(e[0] - em), w1 = __expf(e[1] - em);
        float w2 = __expf(e[2] - em), w3 = __expf(e[3] - em);
        l = l * f + (w0 + w1 + w2 + w3);
        #pragma unroll
        for (int i = 0; i < 8; ++i) {
            float a = acc[i] * f;
            a = fmaf(w0, va[0][i], a);
            a = fmaf(w1, va[1][i], a);
            a = fmaf(w2, va[2][i], a);
            acc[i] = fmaf(w3, va[3][i], a);
        }
        m = em;
    }

    // ---- block-level combine of the 4 wave partials ----
    #pragma unroll
    for (int i = 0; i < 8; ++i) sacc[w][8 * lane + i] = acc[i];
    if (lane == 0) { sml[w] = m; sml[4 + w] = l; }
    __syncthreads();

    const float m0 = sml[0], m1 = sml[1], m2 = sml[2], m3 = sml[3];
    const float ms = fmaxf(fmaxf(m0, m1), fmaxf(m2, m3));
    const float c0 = __expf(m0 - ms), c1 = __expf(m1 - ms);
    const float c2 = __expf(m2 - ms), c3 = __expf(m3 - ms);
    const int t = threadIdx.x;
    #pragma unroll
    for (int i = 0; i < 2; ++i) {
        const int h = t + i * 256;
        float v = c0 * sacc[0][h] + c1 * sacc[1][h]
                + c2 * sacc[2][h] + c3 * sacc[3][h];
        pacc[((size_t)b * P32 + p) * HDIM + h] = v;
    }
    if (t == 0) {
        pm[b * P32 + p] = ms;
        pl[b * P32 + p] = c0 * sml[4] + c1 * sml[5] + c2 * sml[6] + c3 * sml[7];
    }
    __syncthreads();

    // ---- last-block-per-batch fixup: final softmax combine + activations ----
    if (t == 0)
        s_old = __hip_atomic_fetch_add(&ticket[b], 1u, __ATOMIC_ACQ_REL,
                                       __HIP_MEMORY_SCOPE_AGENT);
    __syncthreads();
    if ((s_old & 31u) != 31u) return;

    if (t < 32) {
        float pmv = pm[b * P32 + t];
        float mm = pmv;
        #pragma unroll
        for (int off = 16; off > 0; off >>= 1) mm = fmaxf(mm, __shfl_xor(mm, off, 64));
        float c = __expf(pmv - mm);
        cs[t] = c;
        float d = c * pl[b * P32 + t];
        #pragma unroll
        for (int off = 16; off > 0; off >>= 1) d += __shfl_xor(d, off, 64);
        if (t == 0) s_inv = 1.f / d;
    }
    __syncthreads();

    const float* pa = pacc + (size_t)b * P32 * HDIM;
    #pragma unroll
    for (int i = 0; i < 2; ++i) {
        const int h = t + i * 256;
        float c = 0.f;
        #pragma unroll 8
        for (int pp = 0; pp < P32; ++pp)
            c = fmaf(cs[pp], pa[(size_t)pp * HDIM + h], c);
        xbf[(size_t)b * (EDIM + HDIM) + EDIM + h] = f2bf(c * s_inv);
        d0bf[(size_t)b * HDIM + h] = f2bf(dec[(size_t)b * HDIM + h]);
        d1bf[(size_t)b * HDIM + h] = f2bf(dec[BH + (size_t)b * HDIM + h]);
    }
    if (t < EDIM)
        xbf[(size_t)b * (EDIM + HDIM) + t] = f2bf(emb[(size_t)inputs[b] * EDIM + t]);
}

// ---------------------------------------------------------------------------
// Kernel 3a: GRU gemms (unchanged). grid (48,4) = 192 blocks.
// ---------------------------------------------------------------------------
template<int K1>
__global__ __launch_bounds__(256)
void gru_gemm(const unsigned short* __restrict__ Aih,
              const unsigned short* __restrict__ Ahh,
              const float* __restrict__ Wih,
              const float* __restrict__ Whh,
              float* __restrict__ part) {
    const int lane = threadIdx.x & 63;
    const int nt = blockIdx.x * 4 + (threadIdx.x >> 6);
    const int kc = blockIdx.y;
    const int nn = lane & 15;
    const int koff = (lane >> 4) * 8;

    const bool ih = nt < 96;
    const int col16 = ih ? nt : nt - 96;
    const int g = col16 * 16 + nn;
    const int K = ih ? K1 : HDIM;
    const int kchunk = K >> 2;
    const int k0 = kc * kchunk;

    const float* wrow = (ih ? Wih : Whh) + (size_t)g * K + k0 + koff;
    const unsigned short* arow = (ih ? Aih : Ahh) + (size_t)nn * K + k0 + koff;

    f32x4 acc[4];
    #pragma unroll
    for (int mt = 0; mt < 4; ++mt) acc[mt] = (f32x4){0, 0, 0, 0};

    const int nks = kchunk >> 5;
    #pragma unroll 2
    for (int ks = 0; ks < nks; ++ks) {
        bf16x8 bf = cvt8(wrow + 32 * ks);
        #pragma unroll
        for (int mt = 0; mt < 4; ++mt) {
            bf16x8 a = *(const bf16x8*)(arow + (size_t)mt * 16 * K + 32 * ks);
            acc[mt] = __builtin_amdgcn_mfma_f32_16x16x32_bf16(a, bf, acc[mt], 0, 0, 0);
        }
    }

    const int col = col16 * 16 + nn + (ih ? 0 : G3);
    float* pp = part + ((size_t)kc * NCOL + col) * 64 + (lane >> 4) * 4;
    #pragma unroll
    for (int mt = 0; mt < 4; ++mt)
        *(f32x4*)(pp + mt * 16) = acc[mt];
}

// ---------------------------------------------------------------------------
// Kernel 3b: GRU gate math (unchanged).
// ---------------------------------------------------------------------------
__global__ __launch_bounds__(256)
void gru_gate(const float* __restrict__ part,
              const float* __restrict__ hprev,
              const float* __restrict__ bih, const float* __restrict__ bhh,
              float* __restrict__ hout, unsigned short* __restrict__ houtBf) {
    const int gidx = blockIdx.x * 256 + threadIdx.x;
    const int b = gidx & 63;
    const int h = gidx >> 6;

    #define PRD(c) (part[(size_t)(c) * 64 + b] \
                  + part[((size_t)NCOL + (c)) * 64 + b] \
                  + part[((size_t)2 * NCOL + (c)) * 64 + b] \
                  + part[((size_t)3 * NCOL + (c)) * 64 + b])
    float ir = PRD(h),             hr = PRD(G3 + h);
    float iz = PRD(HDIM + h),      hz = PRD(G3 + HDIM + h);
    float in_ = PRD(2 * HDIM + h), hn = PRD(G3 + 2 * HDIM + h);
    #undef PRD

    float r = 1.f / (1.f + __expf(-(ir + bih[h] + hr + bhh[h])));
    float z = 1.f / (1.f + __expf(-(iz + bih[HDIM + h] + hz + bhh[HDIM + h])));
    float n = tanhf(in_ + bih[2 * HDIM + h] + r * (hn + bhh[2 * HDIM + h]));
    float hp = hprev[(size_t)b * HDIM + h];
    float hnew = (1.f - z) * n + z * hp;

    hout[(size_t)b * HDIM + h] = hnew;
    houtBf[(size_t)b * HDIM + h] = f2bf(hnew);
}

// ---------------------------------------------------------------------------
// Kernel 4: vocab projection (unchanged): A staged in LDS w/ XOR swizzle,
// W register-direct depth-3 ring.
// ---------------------------------------------------------------------------
__global__ __launch_bounds__(256)
void vocab_proj_mfma(const unsigned short* __restrict__ h1bf,
                     const float* __restrict__ Wout,
                     const float* __restrict__ bout,
                     float* __restrict__ logits) {
    __shared__ uint4 sh4[4096];                 // 64KB: h1 [64 rows][64 slots]
    const int t = threadIdx.x;
    const uint4* g4 = (const uint4*)h1bf;
    #pragma unroll
    for (int i = 0; i < 16; ++i) {
        int q = i * 256 + t;
        int r = q >> 6, s = q & 63;
        sh4[(r << 6) | (s ^ (r & 15))] = g4[q];
    }
    __syncthreads();

    const int NT = (VOCAB + 15) / 16;           // 3142
    const int lane = t & 63;
    const int nt = blockIdx.x * 4 + (t >> 6);
    if (nt >= NT) return;

    const int nn = lane & 15;
    const int koff16 = lane >> 4;
    const int v  = nt * 16 + nn;
    const int vclamp = min(v, VOCAB - 1);

    const float* wrow = Wout + (size_t)vclamp * HDIM + koff16 * 8;

    f32x4 acc[4];
    #pragma unroll
    for (int mt = 0; mt < 4; ++mt) acc[mt] = (f32x4){0, 0, 0, 0};

    float4 pw0[3], pw1[3];
    #pragma unroll
    for (int d = 0; d < 3; ++d) {
        pw0[d] = *(const float4*)(wrow + 32 * d);
        pw1[d] = *(const float4*)(wrow + 32 * d + 4);
    }

    #pragma unroll
    for (int ks = 0; ks < 16; ++ks) {
        const int slot = ks % 3;
        bf16x8 bfrag = pack8(pw0[slot], pw1[slot]);
        if (ks + 3 < 16) {
            pw0[slot] = *(const float4*)(wrow + 32 * (ks + 3));
            pw1[slot] = *(const float4*)(wrow + 32 * (ks + 3) + 4);
        }
        const int s = 4 * ks + koff16;
        #pragma unroll
        for (int mt = 0; mt < 4; ++mt) {
            const int row = mt * 16 + nn;
            bf16x8 a = *(const bf16x8*)&sh4[(row << 6) | (s ^ nn)];
            acc[mt] = __builtin_amdgcn_mfma_f32_16x16x32_bf16(a, bfrag, acc[mt], 0, 0, 0);
        }
    }

    if (v < VOCAB) {
        const float bias = bout[v];
        const int b0 = koff16 * 4;
        #pragma unroll
        for (int mt = 0; mt < 4; ++mt)
            #pragma unroll
            for (int r = 0; r < 4; ++r)
                logits[(size_t)(mt * 16 + b0 + r) * VOCAB + v] = acc[mt][r] + bias;
    }
}

// ---------------------------------------------------------------------------
extern "C" void kernel_launch(void* const* d_in, const int* in_sizes, int n_in,
                              void* d_out, int out_size, void* d_ws, size_t ws_size,
                              hipStream_t stream) {
    const int*   inputs = (const int*)d_in[0];
    const float* dec    = (const float*)d_in[1];
    const float* enc    = (const float*)d_in[2];
    const float* emb    = (const float*)d_in[3];
    const float* Wih0   = (const float*)d_in[4];
    const float* Whh0   = (const float*)d_in[5];
    const float* bih0   = (const float*)d_in[6];
    const float* bhh0   = (const float*)d_in[7];
    const float* Wih1   = (const float*)d_in[8];
    const float* Whh1   = (const float*)d_in[9];
    const float* bih1   = (const float*)d_in[10];
    const float* bhh1   = (const float*)d_in[11];
    const float* Wout   = (const float*)d_in[12];
    const float* bout   = (const float*)d_in[13];
    float* out = (float*)d_out;

    unsigned* ticket = (unsigned*)d_ws;                     // [64], any init ok
    float* w    = (float*)((char*)d_ws + 256);
    float* pm   = w;                                        // [64][32]
    float* pl   = pm + (size_t)P32 * BATCH;
    float* pacc = pl + (size_t)P32 * BATCH;                 // [64][32][512]
    float* part = pacc + (size_t)P32 * BATCH * HDIM;        // [KS][3072][64]
    unsigned short* xbf  = (unsigned short*)(part + (size_t)KS * NCOL * 64);
    unsigned short* d0bf = xbf + (size_t)BATCH * (EDIM + HDIM);
    unsigned short* d1bf = d0bf + BH;
    unsigned short* h0bf = d1bf + BH;
    unsigned short* h1bf = h0bf + BH;

    float* h0out = out + (size_t)BATCH * VOCAB;   // new_hidden[0]
    float* h1out = h0out + BH;                    // new_hidden[1]

    attn_partial<<<dim3(P32, BATCH), 256, 0, stream>>>(enc, dec, emb, inputs,
                                                       ticket, pm, pl, pacc,
                                                       xbf, d0bf, d1bf);

    gru_gemm<EDIM + HDIM><<<dim3(48, KS), 256, 0, stream>>>(xbf, d0bf, Wih0, Whh0, part);
    gru_gate<<<128, 256, 0, stream>>>(part, dec, bih0, bhh0, h0out, h0bf);
    gru_gemm<HDIM><<<dim3(48, KS), 256, 0, stream>>>(h0bf, d1bf, Wih1, Whh1, part);
    gru_gate<<<128, 256, 0, stream>>>(part, dec + BH, bih1, bhh1, h1out, h1bf);

    const int NT = (VOCAB + 15) / 16;
    vocab_proj_mfma<<<(NT + 3) / 4, 256, 0, stream>>>(h1bf, Wout, bout, out);
}

// Round 11
// 118.861 us; speedup vs baseline: 1.8139x; 1.8139x over previous
//
#include <hip/hip_runtime.h>
#include <math.h>

#define SEQ   2048
#define BATCH 64
#define HDIM  512
#define EDIM  256
#define VOCAB 50257
#define BH    (BATCH * HDIM)   // 32768
#define G3    (3 * HDIM)       // 1536
#define NCOL  (2 * G3)         // 3072 combined gate columns (ih | hh)
#define P32   32               // block-level partials per batch
#define KS    4                // gru K-chunks

typedef __attribute__((ext_vector_type(4))) float f32x4;
typedef __attribute__((ext_vector_type(8))) short bf16x8;

__device__ __forceinline__ unsigned short f2bf(float x) {
    unsigned int u = __float_as_uint(x);
    u += 0x7fffu + ((u >> 16) & 1u);   // round-to-nearest-even
    return (unsigned short)(u >> 16);
}

__device__ __forceinline__ bf16x8 pack8(float4 a, float4 b) {
    bf16x8 r;
    r[0] = (short)f2bf(a.x); r[1] = (short)f2bf(a.y);
    r[2] = (short)f2bf(a.z); r[3] = (short)f2bf(a.w);
    r[4] = (short)f2bf(b.x); r[5] = (short)f2bf(b.y);
    r[6] = (short)f2bf(b.z); r[7] = (short)f2bf(b.w);
    return r;
}

__device__ __forceinline__ bf16x8 cvt8(const float* p) {
    return pack8(*(const float4*)p, *(const float4*)(p + 4));
}

// ---------------------------------------------------------------------------
// Kernel 1: flash attention partials + block-level (4-wave) LDS combine.
// Plain cached loads; NO atomics (R9/R10 post-mortem: device-scope ACQ_REL
// per block = chip-wide L2 invalidate storm, 4x kernel slowdown).
// ---------------------------------------------------------------------------
__global__ __launch_bounds__(256)
void attn_partial(const float* __restrict__ enc, const float* __restrict__ dec,
                  float* __restrict__ pm, float* __restrict__ pl,
                  float* __restrict__ pacc) {
    const int lane = threadIdx.x & 63;
    const int w = threadIdx.x >> 6;
    const int p = blockIdx.x;            // 0..31
    const int b = blockIdx.y;
    const int s0 = (p * 4 + w) * 16;
    const float scale = 0.044194173824159216f; // 1/sqrt(512)

    const float4* qp = (const float4*)(dec + BH + (size_t)b * HDIM + 8 * lane);
    float4 q0 = qp[0], q1 = qp[1];
    float qa[8] = {q0.x, q0.y, q0.z, q0.w, q1.x, q1.y, q1.z, q1.w};

    float m = -INFINITY, l = 0.f;
    float acc[8] = {0.f, 0.f, 0.f, 0.f, 0.f, 0.f, 0.f, 0.f};

    #pragma unroll 2
    for (int r = 0; r < 16; r += 4) {
        float va[4][8];
        #pragma unroll
        for (int j = 0; j < 4; ++j) {
            const float4* vp = (const float4*)(enc +
                ((size_t)(s0 + r + j) * BATCH + b) * HDIM + 8 * lane);
            float4 t0 = vp[0], t1 = vp[1];
            va[j][0] = t0.x; va[j][1] = t0.y; va[j][2] = t0.z; va[j][3] = t0.w;
            va[j][4] = t1.x; va[j][5] = t1.y; va[j][6] = t1.z; va[j][7] = t1.w;
        }
        float e[4];
        #pragma unroll
        for (int j = 0; j < 4; ++j) {
            float d = 0.f;
            #pragma unroll
            for (int i = 0; i < 8; ++i) d = fmaf(va[j][i], qa[i], d);
            e[j] = d;
        }
        #pragma unroll
        for (int off = 32; off > 0; off >>= 1) {
            #pragma unroll
            for (int j = 0; j < 4; ++j) e[j] += __shfl_xor(e[j], off, 64);
        }
        #pragma unroll
        for (int j = 0; j < 4; ++j) e[j] *= scale;
        float m4 = fmaxf(fmaxf(e[0], e[1]), fmaxf(e[2], e[3]));
        float em = fmaxf(m, m4);
        float f  = __expf(m - em);
        float w0 = __expf(e[0] - em), w1 = __expf(e[1] - em);
        float w2 = __expf(e[2] - em), w3 = __expf(e[3] - em);
        l = l * f + (w0 + w1 + w2 + w3);
        #pragma unroll
        for (int i = 0; i < 8; ++i) {
            float a = acc[i] * f;
            a = fmaf(w0, va[0][i], a);
            a = fmaf(w1, va[1][i], a);
            a = fmaf(w2, va[2][i], a);
            acc[i] = fmaf(w3, va[3][i], a);
        }
        m = em;
    }

    __shared__ float sacc[4][HDIM];
    __shared__ float sml[8];
    #pragma unroll
    for (int i = 0; i < 8; ++i) sacc[w][8 * lane + i] = acc[i];
    if (lane == 0) { sml[w] = m; sml[4 + w] = l; }
    __syncthreads();

    const float m0 = sml[0], m1 = sml[1], m2 = sml[2], m3 = sml[3];
    const float ms = fmaxf(fmaxf(m0, m1), fmaxf(m2, m3));
    const float c0 = __expf(m0 - ms), c1 = __expf(m1 - ms);
    const float c2 = __expf(m2 - ms), c3 = __expf(m3 - ms);
    const int t = threadIdx.x;
    #pragma unroll
    for (int i = 0; i < 2; ++i) {
        const int h = t + i * 256;
        float v = c0 * sacc[0][h] + c1 * sacc[1][h]
                + c2 * sacc[2][h] + c3 * sacc[3][h];
        pacc[((size_t)b * P32 + p) * HDIM + h] = v;
    }
    if (t == 0) {
        pm[b * P32 + p] = ms;
        pl[b * P32 + p] = c0 * sml[4] + c1 * sml[5] + c2 * sml[6] + c3 * sml[7];
    }
}

// ---------------------------------------------------------------------------
// Kernel 2: combine 32 partials -> context (bf16 row-major activations out).
// ---------------------------------------------------------------------------
__global__ __launch_bounds__(512)
void attn_combine(const float* __restrict__ pm, const float* __restrict__ pl,
                  const float* __restrict__ pacc, const float* __restrict__ dec,
                  const float* __restrict__ emb, const int* __restrict__ inputs,
                  unsigned short* __restrict__ xbf,
                  unsigned short* __restrict__ d0bf,
                  unsigned short* __restrict__ d1bf) {
    __shared__ float s_coef[P32];
    __shared__ float s_inv;
    const int b = blockIdx.x;
    const int t = threadIdx.x;

    if (t < 64) {
        float mloc = -INFINITY;
        for (int p = t; p < P32; p += 64) mloc = fmaxf(mloc, pm[b * P32 + p]);
        #pragma unroll
        for (int off = 32; off > 0; off >>= 1) mloc = fmaxf(mloc, __shfl_xor(mloc, off, 64));
        float d = 0.f;
        for (int p = t; p < P32; p += 64) {
            float c = __expf(pm[b * P32 + p] - mloc);
            s_coef[p] = c;
            d = fmaf(c, pl[b * P32 + p], d);
        }
        #pragma unroll
        for (int off = 32; off > 0; off >>= 1) d += __shfl_xor(d, off, 64);
        if (t == 0) s_inv = 1.f / d;
    }
    __syncthreads();

    float c = 0.f;
    const float* pa = pacc + (size_t)b * P32 * HDIM + t;
    #pragma unroll 8
    for (int p = 0; p < P32; ++p) c = fmaf(s_coef[p], pa[(size_t)p * HDIM], c);
    float ctx = c * s_inv;

    xbf[(size_t)b * (EDIM + HDIM) + EDIM + t] = f2bf(ctx);
    if (t < EDIM)
        xbf[(size_t)b * (EDIM + HDIM) + t] = f2bf(emb[(size_t)inputs[b] * EDIM + t]);
    d0bf[(size_t)b * HDIM + t] = f2bf(dec[(size_t)b * HDIM + t]);
    d1bf[(size_t)b * HDIM + t] = f2bf(dec[BH + (size_t)b * HDIM + t]);
}

// ---------------------------------------------------------------------------
// Kernel 3a: GRU gemms. grid (48,4) = 192 blocks.
// ---------------------------------------------------------------------------
template<int K1>
__global__ __launch_bounds__(256)
void gru_gemm(const unsigned short* __restrict__ Aih,
              const unsigned short* __restrict__ Ahh,
              const float* __restrict__ Wih,
              const float* __restrict__ Whh,
              float* __restrict__ part) {
    const int lane = threadIdx.x & 63;
    const int nt = blockIdx.x * 4 + (threadIdx.x >> 6);
    const int kc = blockIdx.y;
    const int nn = lane & 15;
    const int koff = (lane >> 4) * 8;

    const bool ih = nt < 96;
    const int col16 = ih ? nt : nt - 96;
    const int g = col16 * 16 + nn;
    const int K = ih ? K1 : HDIM;
    const int kchunk = K >> 2;
    const int k0 = kc * kchunk;

    const float* wrow = (ih ? Wih : Whh) + (size_t)g * K + k0 + koff;
    const unsigned short* arow = (ih ? Aih : Ahh) + (size_t)nn * K + k0 + koff;

    f32x4 acc[4];
    #pragma unroll
    for (int mt = 0; mt < 4; ++mt) acc[mt] = (f32x4){0, 0, 0, 0};

    const int nks = kchunk >> 5;
    #pragma unroll 2
    for (int ks = 0; ks < nks; ++ks) {
        bf16x8 bf = cvt8(wrow + 32 * ks);
        #pragma unroll
        for (int mt = 0; mt < 4; ++mt) {
            bf16x8 a = *(const bf16x8*)(arow + (size_t)mt * 16 * K + 32 * ks);
            acc[mt] = __builtin_amdgcn_mfma_f32_16x16x32_bf16(a, bf, acc[mt], 0, 0, 0);
        }
    }

    const int col = col16 * 16 + nn + (ih ? 0 : G3);
    float* pp = part + ((size_t)kc * NCOL + col) * 64 + (lane >> 4) * 4;
    #pragma unroll
    for (int mt = 0; mt < 4; ++mt)
        *(f32x4*)(pp + mt * 16) = acc[mt];
}

// ---------------------------------------------------------------------------
// Kernel 3b: GRU gate math.
// ---------------------------------------------------------------------------
__global__ __launch_bounds__(256)
void gru_gate(const float* __restrict__ part,
              const float* __restrict__ hprev,
              const float* __restrict__ bih, const float* __restrict__ bhh,
              float* __restrict__ hout, unsigned short* __restrict__ houtBf) {
    const int gidx = blockIdx.x * 256 + threadIdx.x;
    const int b = gidx & 63;
    const int h = gidx >> 6;

    #define PRD(c) (part[(size_t)(c) * 64 + b] \
                  + part[((size_t)NCOL + (c)) * 64 + b] \
                  + part[((size_t)2 * NCOL + (c)) * 64 + b] \
                  + part[((size_t)3 * NCOL + (c)) * 64 + b])
    float ir = PRD(h),             hr = PRD(G3 + h);
    float iz = PRD(HDIM + h),      hz = PRD(G3 + HDIM + h);
    float in_ = PRD(2 * HDIM + h), hn = PRD(G3 + 2 * HDIM + h);
    #undef PRD

    float r = 1.f / (1.f + __expf(-(ir + bih[h] + hr + bhh[h])));
    float z = 1.f / (1.f + __expf(-(iz + bih[HDIM + h] + hz + bhh[HDIM + h])));
    float n = tanhf(in_ + bih[2 * HDIM + h] + r * (hn + bhh[2 * HDIM + h]));
    float hp = hprev[(size_t)b * HDIM + h];
    float hnew = (1.f - z) * n + z * hp;

    hout[(size_t)b * HDIM + h] = hnew;
    houtBf[(size_t)b * HDIM + h] = f2bf(hnew);
}

// ---------------------------------------------------------------------------
// Kernel 4: vocab projection: A staged in LDS w/ XOR swizzle, W
// register-direct depth-3 prefetch ring.
// ---------------------------------------------------------------------------
__global__ __launch_bounds__(256)
void vocab_proj_mfma(const unsigned short* __restrict__ h1bf,
                     const float* __restrict__ Wout,
                     const float* __restrict__ bout,
                     float* __restrict__ logits) {
    __shared__ uint4 sh4[4096];                 // 64KB: h1 [64 rows][64 slots]
    const int t = threadIdx.x;
    const uint4* g4 = (const uint4*)h1bf;
    #pragma unroll
    for (int i = 0; i < 16; ++i) {
        int q = i * 256 + t;
        int r = q >> 6, s = q & 63;
        sh4[(r << 6) | (s ^ (r & 15))] = g4[q];
    }
    __syncthreads();

    const int NT = (VOCAB + 15) / 16;           // 3142
    const int lane = t & 63;
    const int nt = blockIdx.x * 4 + (t >> 6);
    if (nt >= NT) return;

    const int nn = lane & 15;
    const int koff16 = lane >> 4;
    const int v  = nt * 16 + nn;
    const int vclamp = min(v, VOCAB - 1);

    const float* wrow = Wout + (size_t)vclamp * HDIM + koff16 * 8;

    f32x4 acc[4];
    #pragma unroll
    for (int mt = 0; mt < 4; ++mt) acc[mt] = (f32x4){0, 0, 0, 0};

    float4 pw0[3], pw1[3];
    #pragma unroll
    for (int d = 0; d < 3; ++d) {
        pw0[d] = *(const float4*)(wrow + 32 * d);
        pw1[d] = *(const float4*)(wrow + 32 * d + 4);
    }

    #pragma unroll
    for (int ks = 0; ks < 16; ++ks) {
        const int slot = ks % 3;
        bf16x8 bfrag = pack8(pw0[slot], pw1[slot]);
        if (ks + 3 < 16) {
            pw0[slot] = *(const float4*)(wrow + 32 * (ks + 3));
            pw1[slot] = *(const float4*)(wrow + 32 * (ks + 3) + 4);
        }
        const int s = 4 * ks + koff16;
        #pragma unroll
        for (int mt = 0; mt < 4; ++mt) {
            const int row = mt * 16 + nn;
            bf16x8 a = *(const bf16x8*)&sh4[(row << 6) | (s ^ nn)];
            acc[mt] = __builtin_amdgcn_mfma_f32_16x16x32_bf16(a, bfrag, acc[mt], 0, 0, 0);
        }
    }

    if (v < VOCAB) {
        const float bias = bout[v];
        const int b0 = koff16 * 4;
        #pragma unroll
        for (int mt = 0; mt < 4; ++mt)
            #pragma unroll
            for (int r = 0; r < 4; ++r)
                logits[(size_t)(mt * 16 + b0 + r) * VOCAB + v] = acc[mt][r] + bias;
    }
}

// ---------------------------------------------------------------------------
extern "C" void kernel_launch(void* const* d_in, const int* in_sizes, int n_in,
                              void* d_out, int out_size, void* d_ws, size_t ws_size,
                              hipStream_t stream) {
    const int*   inputs = (const int*)d_in[0];
    const float* dec    = (const float*)d_in[1];
    const float* enc    = (const float*)d_in[2];
    const float* emb    = (const float*)d_in[3];
    const float* Wih0   = (const float*)d_in[4];
    const float* Whh0   = (const float*)d_in[5];
    const float* bih0   = (const float*)d_in[6];
    const float* bhh0   = (const float*)d_in[7];
    const float* Wih1   = (const float*)d_in[8];
    const float* Whh1   = (const float*)d_in[9];
    const float* bih1   = (const float*)d_in[10];
    const float* bhh1   = (const float*)d_in[11];
    const float* Wout   = (const float*)d_in[12];
    const float* bout   = (const float*)d_in[13];
    float* out = (float*)d_out;

    float* w    = (float*)d_ws;
    float* pm   = w;                                        // [64][32]
    float* pl   = pm + (size_t)P32 * BATCH;
    float* pacc = pl + (size_t)P32 * BATCH;                 // [64][32][512]
    float* part = pacc + (size_t)P32 * BATCH * HDIM;        // [KS][3072][64]
    unsigned short* xbf  = (unsigned short*)(part + (size_t)KS * NCOL * 64);
    unsigned short* d0bf = xbf + (size_t)BATCH * (EDIM + HDIM);
    unsigned short* d1bf = d0bf + BH;
    unsigned short* h0bf = d1bf + BH;
    unsigned short* h1bf = h0bf + BH;

    float* h0out = out + (size_t)BATCH * VOCAB;   // new_hidden[0]
    float* h1out = h0out + BH;                    // new_hidden[1]

    attn_partial<<<dim3(P32, BATCH), 256, 0, stream>>>(enc, dec, pm, pl, pacc);
    attn_combine<<<BATCH, 512, 0, stream>>>(pm, pl, pacc, dec, emb, inputs, xbf, d0bf, d1bf);

    gru_gemm<EDIM + HDIM><<<dim3(48, KS), 256, 0, stream>>>(xbf, d0bf, Wih0, Whh0, part);
    gru_gate<<<128, 256, 0, stream>>>(part, dec, bih0, bhh0, h0out, h0bf);
    gru_gemm<HDIM><<<dim3(48, KS), 256, 0, stream>>>(h0bf, d1bf, Wih1, Whh1, part);
    gru_gate<<<128, 256, 0, stream>>>(part, dec + BH, bih1, bhh1, h1out, h1bf);

    const int NT = (VOCAB + 15) / 16;
    vocab_proj_mfma<<<(NT + 3) / 4, 256, 0, stream>>>(h1bf, Wout, bout, out);
}